// Round 5
// baseline (582.371 us; speedup 1.0000x reference)
//
#include <hip/hip_runtime.h>
#include <hip/hip_bf16.h>

#define CH     96
#define KOFF   27
#define TM     256            // rows per block = 8 waves x 32 rows
#define NCHUNK 1152           // 16B chunks per k weight tile (96x96 bf16, no pad)

typedef __bf16 bf16x8 __attribute__((ext_vector_type(8)));
typedef float  floatx4 __attribute__((ext_vector_type(4)));

typedef const __attribute__((address_space(1))) unsigned int* as1_u32p;
typedef __attribute__((address_space(3))) unsigned int*       as3_u32p;

static __device__ inline uint pk_bf16(float a, float b) {
    __hip_bfloat162 h = __float22bfloat162_rn(make_float2(a, b));
    return *(uint*)&h;
}

// W[k][j][c] fp32 -> bf16 MFMA B-fragment image:
// chunk c in [0,1152): f=c>>6 (f = nt*3+kk), lane=c&63;
// chunk = 8 bf16: W[k][kk*32+(lane>>4)*8 + j][nt*16+(lane&15)], j=0..7
static __device__ inline void frag_block(int k, const float* __restrict__ W1,
                                         const float* __restrict__ W2,
                                         uint4* __restrict__ Wf1,
                                         uint4* __restrict__ Wf2)
{
    const float* src = (k < KOFF) ? (W1 + (size_t)k * CH * CH)
                                  : (W2 + (size_t)(k - KOFF) * CH * CH);
    uint4* dst = ((k < KOFF) ? Wf1 : Wf2) + (size_t)(k % KOFF) * NCHUNK;
    for (int c = threadIdx.x; c < 1152; c += 256) {
        int f    = c >> 6;
        int lane = c & 63;
        int nt = f / 3, kk = f - nt * 3;
        int jb  = kk * 32 + (lane >> 4) * 8;
        int col = nt * 16 + (lane & 15);
        uint p[4];
#pragma unroll
        for (int h = 0; h < 4; ++h)
            p[h] = pk_bf16(src[(size_t)(jb + 2 * h) * CH + col],
                           src[(size_t)(jb + 2 * h + 1) * CH + col]);
        uint4 v; v.x = p[0]; v.y = p[1]; v.z = p[2]; v.w = p[3];
        dst[c] = v;
    }
}

// small prep: blocks [0,54) build weight fragment images; blocks [54,310)
// pack nmask into 27-bit masks, int4 (one shot, no grid-stride tail).
__global__ __launch_bounds__(256) void prep_small(
    const float* __restrict__ W1, const float* __restrict__ W2,
    uint4* __restrict__ Wf1, uint4* __restrict__ Wf2,
    const int* __restrict__ nmask, uint* __restrict__ pb, int N)
{
    const int bid = blockIdx.x;
    if (bid < 2 * KOFF) { frag_block(bid, W1, W2, Wf1, Wf2); return; }
    if (!pb) return;

    const int n4 = N / 4;
    const int i  = (bid - 2 * KOFF) * 256 + threadIdx.x;
    if (i >= n4) return;
    const int4* nm4 = (const int4*)nmask;
    uint m0 = 0, m1 = 0, m2 = 0, m3 = 0;
#pragma unroll
    for (int k = 0; k < KOFF; ++k) {
        int4 v = nm4[(size_t)k * n4 + i];
        m0 |= (v.x != 0 ? 1u : 0u) << k;
        m1 |= (v.y != 0 ? 1u : 0u) << k;
        m2 |= (v.z != 0 ? 1u : 0u) << k;
        m3 |= (v.w != 0 ? 1u : 0u) << k;
    }
    uint4 o; o.x = m0; o.y = m1; o.z = m2; o.w = m3;
    ((uint4*)pb)[i] = o;
}

// PASS 0: fin = fp32 feats -> out bf16 x (exec-masked fp32 gathers, no resid)
// PASS 1: fin = bf16 x     -> out fp32, residual = fp32 feats (pipelined gathers)
template<int PASS>
__global__ __launch_bounds__(512, 4) void sconv(
    const void* __restrict__ fin_,
    const int*  __restrict__ nidx,        // [27][N]
    const int*  __restrict__ nmask,       // [27][N] (used when pb == null)
    const uint* __restrict__ pb,          // packed masks [N]
    const uint4* __restrict__ Wf,         // [27][NCHUNK] fragment image
    const float* __restrict__ bias,
    const float* __restrict__ alpha,
    const float* __restrict__ resid,
    void* __restrict__ fout_,
    int N)
{
    __shared__ uint4 WsL[2 * NCHUNK];     // 36 KB, double-buffered weight tile

    const int tid   = threadIdx.x;
    const int lane  = tid & 63;
    const int wid   = tid >> 6;           // 0..7
    const int quad  = lane >> 4;
    const int col0  = lane & 15;
    const int wbase = blockIdx.x * TM + wid * 32;   // this wave's 32 rows
    const int myrow = wbase + (lane & 31);

    uint mbits;
    if (pb) {
        mbits = pb[myrow];
    } else {
        mbits = 0;
        for (int k = 0; k < KOFF; ++k)
            mbits |= (nmask[(size_t)k * N + myrow] != 0 ? 1u : 0u) << k;
    }
    const uint mb0 = (uint)__shfl((int)mbits, col0, 64);        // rows wbase+col0
    const uint mb1 = (uint)__shfl((int)mbits, 16 + col0, 64);   // rows wbase+16+col0

    // kick weight stage for k=0 into buffer 0 (wave-uniform LDS base + lane*16)
    {
        const uint4* g = Wf;
#pragma unroll
        for (int r = 0; r < 2; ++r) {
            int cbase = r * 512 + wid * 64;
            __builtin_amdgcn_global_load_lds(
                (as1_u32p)(const void*)(g + cbase + lane),
                (as3_u32p)(void*)(&WsL[cbase]), 16, 0, 0);
        }
        if (wid < 2) {
            int cbase = 1024 + wid * 64;
            __builtin_amdgcn_global_load_lds(
                (as1_u32p)(const void*)(g + cbase + lane),
                (as3_u32p)(void*)(&WsL[cbase]), 16, 0, 0);
        }
    }

    floatx4 acc[2][6];
#pragma unroll
    for (int mt = 0; mt < 2; ++mt)
#pragma unroll
        for (int nt = 0; nt < 6; ++nt)
            acc[mt][nt] = (floatx4){0.f, 0.f, 0.f, 0.f};

    if (PASS == 0) {
        // fp32 exec-masked gathers, simple loop (gather prefetch proven neutral)
        int idxv = nidx[myrow];
        for (int k = 0; k < KOFF; ++k) {
            const int buf = k & 1;
            const int i0  = __shfl(idxv, col0, 64);
            const int i1  = __shfl(idxv, 16 + col0, 64);
            const bool s0 = (mb0 >> k) & 1u;
            const bool s1 = (mb1 >> k) & 1u;

            __syncthreads();

            if (k + 1 < KOFF) {
                const uint4* g = Wf + (size_t)(k + 1) * NCHUNK;
                const int dst = (buf ^ 1) * NCHUNK;
#pragma unroll
                for (int r = 0; r < 2; ++r) {
                    int cbase = r * 512 + wid * 64;
                    __builtin_amdgcn_global_load_lds(
                        (as1_u32p)(const void*)(g + cbase + lane),
                        (as3_u32p)(void*)(&WsL[dst + cbase]), 16, 0, 0);
                }
                if (wid < 2) {
                    int cbase = 1024 + wid * 64;
                    __builtin_amdgcn_global_load_lds(
                        (as1_u32p)(const void*)(g + cbase + lane),
                        (as3_u32p)(void*)(&WsL[dst + cbase]), 16, 0, 0);
                }
                idxv = nidx[(size_t)(k + 1) * N + myrow];
            }

#pragma unroll
            for (int kk = 0; kk < 3; ++kk) {
                uint4 r0 = {0, 0, 0, 0}, r1 = {0, 0, 0, 0};
                const float4* fs = (const float4*)fin_;
                if (s0) {
                    float4 lo = fs[(size_t)i0 * 24 + kk * 8 + quad * 2];
                    float4 hi = fs[(size_t)i0 * 24 + kk * 8 + quad * 2 + 1];
                    r0.x = pk_bf16(lo.x, lo.y); r0.y = pk_bf16(lo.z, lo.w);
                    r0.z = pk_bf16(hi.x, hi.y); r0.w = pk_bf16(hi.z, hi.w);
                }
                if (s1) {
                    float4 lo = fs[(size_t)i1 * 24 + kk * 8 + quad * 2];
                    float4 hi = fs[(size_t)i1 * 24 + kk * 8 + quad * 2 + 1];
                    r1.x = pk_bf16(lo.x, lo.y); r1.y = pk_bf16(lo.z, lo.w);
                    r1.z = pk_bf16(hi.x, hi.y); r1.w = pk_bf16(hi.z, hi.w);
                }
                bf16x8 a0 = *(bf16x8*)&r0;
                bf16x8 a1 = *(bf16x8*)&r1;
#pragma unroll
                for (int nt = 0; nt < 6; ++nt) {
                    bf16x8 b = *(bf16x8*)&WsL[buf * NCHUNK + (nt * 3 + kk) * 64 + lane];
                    acc[0][nt] = __builtin_amdgcn_mfma_f32_16x16x32_bf16(a0, b, acc[0][nt], 0, 0, 0);
                    acc[1][nt] = __builtin_amdgcn_mfma_f32_16x16x32_bf16(a1, b, acc[1][nt], 0, 0, 0);
                }
            }
        }
    } else {
        // bf16 gathers pipelined one k ahead (issue-early, consume-late)
        const uint4* xs = (const uint4*)fin_;
        int idx_cur = nidx[myrow];
        uint4 gc0[3], gc1[3];
        {
            const int i0 = __shfl(idx_cur, col0, 64);
            const int i1 = __shfl(idx_cur, 16 + col0, 64);
            const bool s0 = mb0 & 1u;
            const bool s1 = mb1 & 1u;
#pragma unroll
            for (int kk = 0; kk < 3; ++kk) {
                gc0[kk] = (uint4){0, 0, 0, 0};
                gc1[kk] = (uint4){0, 0, 0, 0};
                if (s0) gc0[kk] = xs[(size_t)i0 * 12 + kk * 4 + quad];
                if (s1) gc1[kk] = xs[(size_t)i1 * 12 + kk * 4 + quad];
            }
        }
        int idx_nxt = nidx[(size_t)N + myrow];   // k = 1

        for (int k = 0; k < KOFF; ++k) {
            const int buf = k & 1;

            __syncthreads();   // W[k] staged; g[k] gathers complete (vmcnt drain)

            uint4 gn0[3], gn1[3];
            if (k + 1 < KOFF) {
                const uint4* g = Wf + (size_t)(k + 1) * NCHUNK;
                const int dst = (buf ^ 1) * NCHUNK;
#pragma unroll
                for (int r = 0; r < 2; ++r) {
                    int cbase = r * 512 + wid * 64;
                    __builtin_amdgcn_global_load_lds(
                        (as1_u32p)(const void*)(g + cbase + lane),
                        (as3_u32p)(void*)(&WsL[dst + cbase]), 16, 0, 0);
                }
                if (wid < 2) {
                    int cbase = 1024 + wid * 64;
                    __builtin_amdgcn_global_load_lds(
                        (as1_u32p)(const void*)(g + cbase + lane),
                        (as3_u32p)(void*)(&WsL[dst + cbase]), 16, 0, 0);
                }
                const int i0n = __shfl(idx_nxt, col0, 64);
                const int i1n = __shfl(idx_nxt, 16 + col0, 64);
                const bool t0 = (mb0 >> (k + 1)) & 1u;
                const bool t1 = (mb1 >> (k + 1)) & 1u;
#pragma unroll
                for (int kk = 0; kk < 3; ++kk) {
                    gn0[kk] = (uint4){0, 0, 0, 0};
                    gn1[kk] = (uint4){0, 0, 0, 0};
                    if (t0) gn0[kk] = xs[(size_t)i0n * 12 + kk * 4 + quad];
                    if (t1) gn1[kk] = xs[(size_t)i1n * 12 + kk * 4 + quad];
                }
                if (k + 2 < KOFF) idx_nxt = nidx[(size_t)(k + 2) * N + myrow];
            }

#pragma unroll
            for (int kk = 0; kk < 3; ++kk) {
                bf16x8 a0 = *(bf16x8*)&gc0[kk];
                bf16x8 a1 = *(bf16x8*)&gc1[kk];
#pragma unroll
                for (int nt = 0; nt < 6; ++nt) {
                    bf16x8 b = *(bf16x8*)&WsL[buf * NCHUNK + (nt * 3 + kk) * 64 + lane];
                    acc[0][nt] = __builtin_amdgcn_mfma_f32_16x16x32_bf16(a0, b, acc[0][nt], 0, 0, 0);
                    acc[1][nt] = __builtin_amdgcn_mfma_f32_16x16x32_bf16(a1, b, acc[1][nt], 0, 0, 0);
                }
            }

            if (k + 1 < KOFF) {
#pragma unroll
                for (int kk = 0; kk < 3; ++kk) {
                    gc0[kk] = gn0[kk];
                    gc1[kk] = gn1[kk];
                }
            }
        }
    }

    const float al = alpha[0];
#pragma unroll
    for (int mt = 0; mt < 2; ++mt) {
#pragma unroll
        for (int nt = 0; nt < 6; ++nt) {
            const int c  = nt * 16 + col0;
            const float bv = bias[c];
#pragma unroll
            for (int rr = 0; rr < 4; ++rr) {
                const int row = wbase + mt * 16 + quad * 4 + rr;
                float v = acc[mt][nt][rr] + bv;
                if (PASS == 1) v += resid[(size_t)row * CH + c];
                v = (v > 0.f) ? v : al * v;
                if (PASS == 1) {
                    ((float*)fout_)[(size_t)row * CH + c] = v;
                } else {
                    __hip_bfloat16 h = __float2bfloat16(v);
                    ((ushort*)fout_)[(size_t)row * CH + c] = *(ushort*)&h;
                }
            }
        }
    }
}

extern "C" void kernel_launch(void* const* d_in, const int* in_sizes, int n_in,
                              void* d_out, int out_size, void* d_ws, size_t ws_size,
                              hipStream_t stream)
{
    const float* feats = (const float*)d_in[0];
    const int*   nidx  = (const int*)d_in[1];
    const int*   nmask = (const int*)d_in[2];
    const float* W1    = (const float*)d_in[3];
    const float* b1    = (const float*)d_in[4];
    const float* a1    = (const float*)d_in[5];
    const float* W2    = (const float*)d_in[6];
    const float* b2    = (const float*)d_in[7];
    const float* a2    = (const float*)d_in[8];

    const int N = in_sizes[0] / CH;   // 262144

    // workspace: Wf1 | Wf2 | x (bf16 intermediate) | pb (packed masks)
    uint4*  Wf1 = (uint4*)d_ws;
    uint4*  Wf2 = Wf1 + (size_t)KOFF * NCHUNK;
    ushort* x   = (ushort*)(Wf2 + (size_t)KOFF * NCHUNK);
    uint*   pb  = (uint*)(x + (size_t)N * CH);
    const size_t need_full = (size_t)((char*)(pb + N) - (char*)d_ws);
    if (ws_size < need_full) pb = nullptr;   // fallback: read nmask in-kernel

    const int packBlocks = (N / 4 + 255) / 256;
    prep_small<<<2 * KOFF + (pb ? packBlocks : 0), 256, 0, stream>>>(
        W1, W2, Wf1, Wf2, nmask, pb, N);

    sconv<0><<<N / TM, 512, 0, stream>>>(
        (const void*)feats, nidx, nmask, pb, Wf1, b1, a1, nullptr, (void*)x, N);
    sconv<1><<<N / TM, 512, 0, stream>>>(
        (const void*)x, nidx, nmask, pb, Wf2, b2, a2, feats, d_out, N);
}

// Round 6
// 524.646 us; speedup vs baseline: 1.1100x; 1.1100x over previous
//
#include <hip/hip_runtime.h>
#include <hip/hip_bf16.h>

#define CH     96
#define KOFF   27
#define TM     256            // rows per block = 8 waves x 32 rows
#define NCHUNK 1152           // 16B chunks per k weight tile (96x96 bf16, no pad)

typedef __bf16 bf16x8 __attribute__((ext_vector_type(8)));
typedef float  floatx4 __attribute__((ext_vector_type(4)));

typedef const __attribute__((address_space(1))) unsigned int* as1_u32p;
typedef __attribute__((address_space(3))) unsigned int*       as3_u32p;

static __device__ inline uint pk_bf16(float a, float b) {
    __hip_bfloat162 h = __float22bfloat162_rn(make_float2(a, b));
    return *(uint*)&h;
}

// W[k][j][c] fp32 -> bf16 MFMA B-fragment image:
// chunk c in [0,1152): f=c>>6 (f = nt*3+kk), lane=c&63;
// chunk = 8 bf16: W[k][kk*32+(lane>>4)*8 + j][nt*16+(lane&15)], j=0..7
static __device__ inline void frag_block(int k, const float* __restrict__ W1,
                                         const float* __restrict__ W2,
                                         uint4* __restrict__ Wf1,
                                         uint4* __restrict__ Wf2)
{
    const float* src = (k < KOFF) ? (W1 + (size_t)k * CH * CH)
                                  : (W2 + (size_t)(k - KOFF) * CH * CH);
    uint4* dst = ((k < KOFF) ? Wf1 : Wf2) + (size_t)(k % KOFF) * NCHUNK;
    for (int c = threadIdx.x; c < 1152; c += 256) {
        int f    = c >> 6;
        int lane = c & 63;
        int nt = f / 3, kk = f - nt * 3;
        int jb  = kk * 32 + (lane >> 4) * 8;
        int col = nt * 16 + (lane & 15);
        uint p[4];
#pragma unroll
        for (int h = 0; h < 4; ++h)
            p[h] = pk_bf16(src[(size_t)(jb + 2 * h) * CH + col],
                           src[(size_t)(jb + 2 * h + 1) * CH + col]);
        uint4 v; v.x = p[0]; v.y = p[1]; v.z = p[2]; v.w = p[3];
        dst[c] = v;
    }
}

// merged prepass: blocks [0,54) build weight fragment images; the rest
// convert feats fp32 -> bf16 table and pack nmask into 27-bit masks (int4).
__global__ __launch_bounds__(256) void prep_all(
    const float* __restrict__ W1, const float* __restrict__ W2,
    uint4* __restrict__ Wf1, uint4* __restrict__ Wf2,
    const float* __restrict__ feats, const int* __restrict__ nmask,
    uint4* __restrict__ xb, uint* __restrict__ pb, int N)
{
    const int bid = blockIdx.x;
    if (bid < 2 * KOFF) { frag_block(bid, W1, W2, Wf1, Wf2); return; }

    const int tid    = (bid - 2 * KOFF) * 256 + threadIdx.x;
    const int stride = (gridDim.x - 2 * KOFF) * 256;
    const int nv = N * (CH / 8);
    const float4* fs = (const float4*)feats;
    for (int i = tid; i < nv; i += stride) {
        float4 lo = fs[(size_t)2 * i], hi = fs[(size_t)2 * i + 1];
        uint4 v;
        v.x = pk_bf16(lo.x, lo.y); v.y = pk_bf16(lo.z, lo.w);
        v.z = pk_bf16(hi.x, hi.y); v.w = pk_bf16(hi.z, hi.w);
        xb[i] = v;
    }
    const int4* nm4 = (const int4*)nmask;
    const int n4 = N / 4;
    for (int i = tid; i < n4; i += stride) {
        uint m0 = 0, m1 = 0, m2 = 0, m3 = 0;
#pragma unroll
        for (int k = 0; k < KOFF; ++k) {
            int4 v = nm4[(size_t)k * n4 + i];
            m0 |= (v.x != 0 ? 1u : 0u) << k;
            m1 |= (v.y != 0 ? 1u : 0u) << k;
            m2 |= (v.z != 0 ? 1u : 0u) << k;
            m3 |= (v.w != 0 ? 1u : 0u) << k;
        }
        uint4 o; o.x = m0; o.y = m1; o.z = m2; o.w = m3;
        ((uint4*)pb)[i] = o;
    }
}

// standalone frag builder (fallback path when workspace too small for xb/pb)
__global__ __launch_bounds__(256) void make_frags(
    const float* __restrict__ W1, const float* __restrict__ W2,
    uint4* __restrict__ Wf1, uint4* __restrict__ Wf2)
{
    frag_block(blockIdx.x, W1, W2, Wf1, Wf2);
}

// PASS 0: fin = bf16 xb  -> out bf16 x (no residual)
// PASS 1: fin = bf16 x   -> out fp32, residual = fp32 feats
// PASS 2: fin = fp32 feats -> out bf16 x (fallback when ws too small for xb/pb)
template<int PASS>
__global__ __launch_bounds__(512, 4) void sconv(
    const void* __restrict__ fin_,
    const int*  __restrict__ nidx,        // [27][N]
    const int*  __restrict__ nmask,       // [27][N] (fallback only)
    const uint* __restrict__ pb,          // packed masks [N] (full path)
    const uint4* __restrict__ Wf,         // [27][NCHUNK] fragment image
    const float* __restrict__ bias,
    const float* __restrict__ alpha,
    const float* __restrict__ resid,
    void* __restrict__ fout_,
    int N)
{
    __shared__ uint4 WsL[2 * NCHUNK];     // 36 KB, double-buffered weight tile

    const int tid   = threadIdx.x;
    const int lane  = tid & 63;
    const int wid   = tid >> 6;           // 0..7
    const int quad  = lane >> 4;
    const int col0  = lane & 15;
    const int wbase = blockIdx.x * TM + wid * 32;   // this wave's 32 rows
    const int myrow = wbase + (lane & 31);

    uint mbits;
    if (pb) {
        mbits = pb[myrow];
    } else {
        mbits = 0;
        for (int k = 0; k < KOFF; ++k)
            mbits |= (nmask[(size_t)k * N + myrow] != 0 ? 1u : 0u) << k;
    }
    const uint mb0 = (uint)__shfl((int)mbits, col0, 64);        // rows wbase+col0
    const uint mb1 = (uint)__shfl((int)mbits, 16 + col0, 64);   // rows wbase+16+col0

    // kick weight stage for k=0 into buffer 0 (wave-uniform LDS base + lane*16)
    {
        const uint4* g = Wf;
#pragma unroll
        for (int r = 0; r < 2; ++r) {
            int cbase = r * 512 + wid * 64;
            __builtin_amdgcn_global_load_lds(
                (as1_u32p)(const void*)(g + cbase + lane),
                (as3_u32p)(void*)(&WsL[cbase]), 16, 0, 0);
        }
        if (wid < 2) {
            int cbase = 1024 + wid * 64;
            __builtin_amdgcn_global_load_lds(
                (as1_u32p)(const void*)(g + cbase + lane),
                (as3_u32p)(void*)(&WsL[cbase]), 16, 0, 0);
        }
    }

    floatx4 acc[2][6];
#pragma unroll
    for (int mt = 0; mt < 2; ++mt)
#pragma unroll
        for (int nt = 0; nt < 6; ++nt)
            acc[mt][nt] = (floatx4){0.f, 0.f, 0.f, 0.f};

    if (PASS == 2) {
        // fallback: fp32 gathers, no prefetch pipeline
        int idxv = nidx[myrow];
        for (int k = 0; k < KOFF; ++k) {
            const int buf = k & 1;
            const int i0  = __shfl(idxv, col0, 64);
            const int i1  = __shfl(idxv, 16 + col0, 64);
            const bool s0 = (mb0 >> k) & 1u;
            const bool s1 = (mb1 >> k) & 1u;

            __syncthreads();

            if (k + 1 < KOFF) {
                const uint4* g = Wf + (size_t)(k + 1) * NCHUNK;
                const int dst = (buf ^ 1) * NCHUNK;
#pragma unroll
                for (int r = 0; r < 2; ++r) {
                    int cbase = r * 512 + wid * 64;
                    __builtin_amdgcn_global_load_lds(
                        (as1_u32p)(const void*)(g + cbase + lane),
                        (as3_u32p)(void*)(&WsL[dst + cbase]), 16, 0, 0);
                }
                if (wid < 2) {
                    int cbase = 1024 + wid * 64;
                    __builtin_amdgcn_global_load_lds(
                        (as1_u32p)(const void*)(g + cbase + lane),
                        (as3_u32p)(void*)(&WsL[dst + cbase]), 16, 0, 0);
                }
                idxv = nidx[(size_t)(k + 1) * N + myrow];
            }

#pragma unroll
            for (int kk = 0; kk < 3; ++kk) {
                uint4 r0 = {0, 0, 0, 0}, r1 = {0, 0, 0, 0};
                const float4* fs = (const float4*)fin_;
                if (s0) {
                    float4 lo = fs[(size_t)i0 * 24 + kk * 8 + quad * 2];
                    float4 hi = fs[(size_t)i0 * 24 + kk * 8 + quad * 2 + 1];
                    r0.x = pk_bf16(lo.x, lo.y); r0.y = pk_bf16(lo.z, lo.w);
                    r0.z = pk_bf16(hi.x, hi.y); r0.w = pk_bf16(hi.z, hi.w);
                }
                if (s1) {
                    float4 lo = fs[(size_t)i1 * 24 + kk * 8 + quad * 2];
                    float4 hi = fs[(size_t)i1 * 24 + kk * 8 + quad * 2 + 1];
                    r1.x = pk_bf16(lo.x, lo.y); r1.y = pk_bf16(lo.z, lo.w);
                    r1.z = pk_bf16(hi.x, hi.y); r1.w = pk_bf16(hi.z, hi.w);
                }
                bf16x8 a0 = *(bf16x8*)&r0;
                bf16x8 a1 = *(bf16x8*)&r1;
#pragma unroll
                for (int nt = 0; nt < 6; ++nt) {
                    bf16x8 b = *(bf16x8*)&WsL[buf * NCHUNK + (nt * 3 + kk) * 64 + lane];
                    acc[0][nt] = __builtin_amdgcn_mfma_f32_16x16x32_bf16(a0, b, acc[0][nt], 0, 0, 0);
                    acc[1][nt] = __builtin_amdgcn_mfma_f32_16x16x32_bf16(a1, b, acc[1][nt], 0, 0, 0);
                }
            }
        }
    } else {
        // full path: bf16 gathers pipelined one k ahead (issue-early, consume-late).
        // gathers for k+1 are issued right after the k-barrier; the implicit
        // vmcnt(0) drain at the NEXT barrier guarantees they are resident, so
        // each gather gets a full compute phase of latency cover.
        const uint4* xs = (const uint4*)fin_;
        int idx_cur = nidx[myrow];
        uint4 gc0[3], gc1[3];
        {
            const int i0 = __shfl(idx_cur, col0, 64);
            const int i1 = __shfl(idx_cur, 16 + col0, 64);
            const bool s0 = mb0 & 1u;
            const bool s1 = mb1 & 1u;
#pragma unroll
            for (int kk = 0; kk < 3; ++kk) {
                gc0[kk] = (uint4){0, 0, 0, 0};
                gc1[kk] = (uint4){0, 0, 0, 0};
                if (s0) gc0[kk] = xs[(size_t)i0 * 12 + kk * 4 + quad];
                if (s1) gc1[kk] = xs[(size_t)i1 * 12 + kk * 4 + quad];
            }
        }
        int idx_nxt = nidx[(size_t)N + myrow];   // k = 1

        for (int k = 0; k < KOFF; ++k) {
            const int buf = k & 1;

            __syncthreads();   // W[k] staged; g[k] gathers complete (vmcnt drain)

            uint4 gn0[3], gn1[3];
            if (k + 1 < KOFF) {
                const uint4* g = Wf + (size_t)(k + 1) * NCHUNK;
                const int dst = (buf ^ 1) * NCHUNK;
#pragma unroll
                for (int r = 0; r < 2; ++r) {
                    int cbase = r * 512 + wid * 64;
                    __builtin_amdgcn_global_load_lds(
                        (as1_u32p)(const void*)(g + cbase + lane),
                        (as3_u32p)(void*)(&WsL[dst + cbase]), 16, 0, 0);
                }
                if (wid < 2) {
                    int cbase = 1024 + wid * 64;
                    __builtin_amdgcn_global_load_lds(
                        (as1_u32p)(const void*)(g + cbase + lane),
                        (as3_u32p)(void*)(&WsL[dst + cbase]), 16, 0, 0);
                }
                const int i0n = __shfl(idx_nxt, col0, 64);
                const int i1n = __shfl(idx_nxt, 16 + col0, 64);
                const bool t0 = (mb0 >> (k + 1)) & 1u;
                const bool t1 = (mb1 >> (k + 1)) & 1u;
#pragma unroll
                for (int kk = 0; kk < 3; ++kk) {
                    gn0[kk] = (uint4){0, 0, 0, 0};
                    gn1[kk] = (uint4){0, 0, 0, 0};
                    if (t0) gn0[kk] = xs[(size_t)i0n * 12 + kk * 4 + quad];
                    if (t1) gn1[kk] = xs[(size_t)i1n * 12 + kk * 4 + quad];
                }
                if (k + 2 < KOFF) idx_nxt = nidx[(size_t)(k + 2) * N + myrow];
            }

#pragma unroll
            for (int kk = 0; kk < 3; ++kk) {
                bf16x8 a0 = *(bf16x8*)&gc0[kk];
                bf16x8 a1 = *(bf16x8*)&gc1[kk];
#pragma unroll
                for (int nt = 0; nt < 6; ++nt) {
                    bf16x8 b = *(bf16x8*)&WsL[buf * NCHUNK + (nt * 3 + kk) * 64 + lane];
                    acc[0][nt] = __builtin_amdgcn_mfma_f32_16x16x32_bf16(a0, b, acc[0][nt], 0, 0, 0);
                    acc[1][nt] = __builtin_amdgcn_mfma_f32_16x16x32_bf16(a1, b, acc[1][nt], 0, 0, 0);
                }
            }

            if (k + 1 < KOFF) {
#pragma unroll
                for (int kk = 0; kk < 3; ++kk) {
                    gc0[kk] = gn0[kk];
                    gc1[kk] = gn1[kk];
                }
            }
        }
    }

    const float al = alpha[0];
#pragma unroll
    for (int mt = 0; mt < 2; ++mt) {
#pragma unroll
        for (int nt = 0; nt < 6; ++nt) {
            const int c  = nt * 16 + col0;
            const float bv = bias[c];
#pragma unroll
            for (int rr = 0; rr < 4; ++rr) {
                const int row = wbase + mt * 16 + quad * 4 + rr;
                float v = acc[mt][nt][rr] + bv;
                if (PASS == 1) v += resid[(size_t)row * CH + c];
                v = (v > 0.f) ? v : al * v;
                if (PASS == 1) {
                    ((float*)fout_)[(size_t)row * CH + c] = v;
                } else {
                    __hip_bfloat16 h = __float2bfloat16(v);
                    ((ushort*)fout_)[(size_t)row * CH + c] = *(ushort*)&h;
                }
            }
        }
    }
}

extern "C" void kernel_launch(void* const* d_in, const int* in_sizes, int n_in,
                              void* d_out, int out_size, void* d_ws, size_t ws_size,
                              hipStream_t stream)
{
    const float* feats = (const float*)d_in[0];
    const int*   nidx  = (const int*)d_in[1];
    const int*   nmask = (const int*)d_in[2];
    const float* W1    = (const float*)d_in[3];
    const float* b1    = (const float*)d_in[4];
    const float* a1    = (const float*)d_in[5];
    const float* W2    = (const float*)d_in[6];
    const float* b2    = (const float*)d_in[7];
    const float* a2    = (const float*)d_in[8];

    const int N = in_sizes[0] / CH;   // 262144

    // workspace: Wf1 | Wf2 | x (bf16) | xb (bf16 feats) | pb (packed masks)
    uint4*  Wf1 = (uint4*)d_ws;
    uint4*  Wf2 = Wf1 + (size_t)KOFF * NCHUNK;
    ushort* x   = (ushort*)(Wf2 + (size_t)KOFF * NCHUNK);
    ushort* xb  = x + (size_t)N * CH;
    uint*   pb  = (uint*)(xb + (size_t)N * CH);
    const size_t need_full = (size_t)((char*)(pb + N) - (char*)d_ws);
    const bool full = ws_size >= need_full;

    if (full) {
        prep_all<<<2 * KOFF + 2048, 256, 0, stream>>>(
            W1, W2, Wf1, Wf2, feats, nmask, (uint4*)xb, pb, N);
        sconv<0><<<N / TM, 512, 0, stream>>>(
            (const void*)xb, nidx, nullptr, pb, Wf1, b1, a1, nullptr, (void*)x, N);
        sconv<1><<<N / TM, 512, 0, stream>>>(
            (const void*)x, nidx, nullptr, pb, Wf2, b2, a2, feats, d_out, N);
    } else {
        make_frags<<<2 * KOFF, 256, 0, stream>>>(W1, W2, Wf1, Wf2);
        sconv<2><<<N / TM, 512, 0, stream>>>(
            (const void*)feats, nidx, nmask, nullptr, Wf1, b1, a1, nullptr, (void*)x, N);
        sconv<1><<<N / TM, 512, 0, stream>>>(
            (const void*)x, nidx, nmask, nullptr, Wf2, b2, a2, feats, d_out, N);
    }
}